// Round 7
// baseline (1905.997 us; speedup 1.0000x reference)
//
#include <hip/hip_runtime.h>
#include <hip/hip_fp16.h>

#define T_LEN 1024
#define E_DIM 300
#define H_DIM 512
#define D_DIM 1024
#define K_TAGS 12
#define G4 2048   // 4*H

typedef __attribute__((ext_vector_type(8))) short short8x;  // 8 bf16
typedef __attribute__((ext_vector_type(4))) float f32x4;

static __device__ __forceinline__ float frcp(float x){ return __builtin_amdgcn_rcpf(x); }
static __device__ __forceinline__ float sigm(float x){ return frcp(1.f + __expf(-x)); }
// overflow-safe fast tanh
static __device__ __forceinline__ float ftanh(float x){
  const float e = __expf(2.f * fabsf(x));
  const float t = 1.f - 2.f * frcp(e + 1.f);
  return copysignf(t, x);
}
// f32 -> bf16 round-to-nearest-even
static __device__ __forceinline__ unsigned short f2b(float f){
  unsigned u = __float_as_uint(f);
  return (unsigned short)((u + 0x7fffu + ((u >> 16) & 1u)) >> 16);
}
static __device__ __forceinline__ uint4 pack8(const float* s){
  uint4 o;
  o.x = (unsigned)f2b(s[0]) | ((unsigned)f2b(s[1]) << 16);
  o.y = (unsigned)f2b(s[2]) | ((unsigned)f2b(s[3]) << 16);
  o.z = (unsigned)f2b(s[4]) | ((unsigned)f2b(s[5]) << 16);
  o.w = (unsigned)f2b(s[6]) | ((unsigned)f2b(s[7]) << 16);
  return o;
}
static __device__ __forceinline__ uint4 pack8u(const unsigned short* s){
  uint4 o;
  o.x = (unsigned)s[0] | ((unsigned)s[1] << 16);
  o.y = (unsigned)s[2] | ((unsigned)s[3] << 16);
  o.z = (unsigned)s[4] | ((unsigned)s[5] << 16);
  o.w = (unsigned)s[6] | ((unsigned)s[7] << 16);
  return o;
}

// ---------------- k_pre: gather + init + Wih casts (one launch) ---------------
// grid 600 x 256
__global__ __launch_bounds__(256) void k_pre(
    const int* __restrict__ sent, const float* __restrict__ we,
    unsigned short* __restrict__ xh,
    const float* __restrict__ Wf, unsigned short* __restrict__ Wfh,
    const float* __restrict__ Wb, unsigned short* __restrict__ Wbh,
    unsigned* __restrict__ hbuf, unsigned* __restrict__ rdy)
{
  const int i = blockIdx.x*256 + threadIdx.x;
  if (i < 2048) hbuf[i] = 0u;           // tag 0, bf16 +0.0 (also bar words 0..15)
  else if (i < 2080) rdy[i-2048] = 0u;  // xgReady
  for (int g = i; g < T_LEN*E_DIM; g += 600*256){
    int t = g / E_DIM, e = g - t*E_DIM;
    xh[g] = f2b(we[(size_t)sent[t]*E_DIM + e]);
  }
  if (i < 153600){
    const float4 v = *reinterpret_cast<const float4*>(Wf + (size_t)i*4);
    ushort2 a, b;
    a.x = f2b(v.x); a.y = f2b(v.y); b.x = f2b(v.z); b.y = f2b(v.w);
    *reinterpret_cast<ushort2*>(Wfh + (size_t)i*4)     = a;
    *reinterpret_cast<ushort2*>(Wfh + (size_t)i*4 + 2) = b;
    const float4 u = *reinterpret_cast<const float4*>(Wb + (size_t)i*4);
    ushort2 c, d;
    c.x = f2b(u.x); c.y = f2b(u.y); d.x = f2b(u.z); d.y = f2b(u.w);
    *reinterpret_cast<ushort2*>(Wbh + (size_t)i*4)     = c;
    *reinterpret_cast<ushort2*>(Wbh + (size_t)i*4 + 2) = d;
  }
}

// ---------------- fused: persistent LSTM (blocks 0-63) + xg producers ---------
// (verified round 6 structure, byte-identical; + bar-zero epilogue on block 0)
__global__ __launch_bounds__(256, 1) void k_lstm_fused(
    const float* __restrict__ Whh_f, const float* __restrict__ Whh_b,
    const float* __restrict__ bih_f, const float* __restrict__ bhh_f,
    const float* __restrict__ bih_b, const float* __restrict__ bhh_b,
    float* __restrict__ xg_f, float* __restrict__ xg_b,
    const unsigned short* __restrict__ xh,
    const unsigned short* __restrict__ Wih_fh, const unsigned short* __restrict__ Wih_bh,
    unsigned* __restrict__ hbuf, unsigned* __restrict__ xgReady,
    float* __restrict__ enc)
{
  __shared__ __align__(16) unsigned short As[64*40];
  __shared__ __align__(16) unsigned short Bs[64*40];
  __shared__ __align__(16) unsigned short lds_hb[512];  // h_{t-1} as bf16
  __shared__ __align__(16) float raw[64];               // gate pre-activations

  const int tid = threadIdx.x;
  const int wave = tid >> 6, lane = tid & 63;
  const int col = lane & 15, quad = lane >> 4;

  if (blockIdx.x >= 64){
    // ================= xg producer =================
    const int pid = blockIdx.x - 64;     // 0..191
    const int r  = tid >> 2, c8 = (tid & 3) * 8;
    const int wm = (wave >> 1) * 32, wn = (wave & 1) * 32;
    uint4* aw = (uint4*)(As + r*40 + c8);
    uint4* bw = (uint4*)(Bs + r*40 + c8);

    for (int j = pid; j < 1024; j += 192){
      const int bm = j >> 6, rem = j & 63, pdir = rem >> 5, bn = rem & 31;
      const unsigned short* Bh = pdir ? Wih_bh : Wih_fh;
      float* C = pdir ? xg_b : xg_f;
      const int am = pdir ? (1023 - (bm*64 + r)) : (bm*64 + r);
      const unsigned short* arow = xh + (size_t)am*E_DIM;
      const unsigned short* brow = Bh + (size_t)(bn*64 + r)*E_DIM;

      f32x4 acc[2][2];
      #pragma unroll
      for (int i=0;i<2;i++)
        #pragma unroll
        for (int jj=0;jj<2;jj++) acc[i][jj] = (f32x4){0.f,0.f,0.f,0.f};

      for (int k0 = 0; k0 < E_DIM; k0 += 32){
        uint4 avv, bvv;
        if (k0 + 32 <= E_DIM){
          avv = *(const uint4*)(arow + k0 + c8);
          bvv = *(const uint4*)(brow + k0 + c8);
        } else {
          unsigned short ta[8], tb[8];
          #pragma unroll
          for (int i=0;i<8;i++){
            const int kk = k0 + c8 + i;
            ta[i] = (kk < E_DIM) ? arow[kk] : (unsigned short)0;
            tb[i] = (kk < E_DIM) ? brow[kk] : (unsigned short)0;
          }
          avv = pack8u(ta); bvv = pack8u(tb);
        }
        __syncthreads();           // also protects LDS reuse across jobs
        *aw = avv; *bw = bvv;
        __syncthreads();
        const short8x a0 = *(const short8x*)(As + (wm+col)*40    + quad*8);
        const short8x a1 = *(const short8x*)(As + (wm+16+col)*40 + quad*8);
        const short8x b0 = *(const short8x*)(Bs + (wn+col)*40    + quad*8);
        const short8x b1 = *(const short8x*)(Bs + (wn+16+col)*40 + quad*8);
        acc[0][0] = __builtin_amdgcn_mfma_f32_16x16x32_bf16(a0, b0, acc[0][0], 0, 0, 0);
        acc[0][1] = __builtin_amdgcn_mfma_f32_16x16x32_bf16(a0, b1, acc[0][1], 0, 0, 0);
        acc[1][0] = __builtin_amdgcn_mfma_f32_16x16x32_bf16(a1, b0, acc[1][0], 0, 0, 0);
        acc[1][1] = __builtin_amdgcn_mfma_f32_16x16x32_bf16(a1, b1, acc[1][1], 0, 0, 0);
      }
      #pragma unroll
      for (int mt=0;mt<2;mt++)
        #pragma unroll
        for (int nt=0;nt<2;nt++)
          #pragma unroll
          for (int i=0;i<4;i++)
            C[(size_t)(bm*64 + wm + 16*mt + quad*4 + i)*G4 + (bn*64 + wn + 16*nt + col)]
              = acc[mt][nt][i];
      __syncthreads();  // all threads' stores issued+drained before the flag
      if (tid == 0)
        __hip_atomic_fetch_add(&xgReady[pdir*16 + bm], 1u,
                               __ATOMIC_RELEASE, __HIP_MEMORY_SCOPE_AGENT);
    }
    return;
  }

  // ================= lstm (verified structure) =================
  const int dir = blockIdx.x >> 5;
  const int w   = blockIdx.x & 31;

  const float* Whh = dir ? Whh_b : Whh_f;
  const float* xg  = dir ? xg_b  : xg_f;
  unsigned* rdy = xgReady + dir*16;

  // ---- A-frag preload: wave 'wave' = gate, rows rowA = gate*512 + w*16 + col
  const int rowA = wave*H_DIM + w*16 + col;
  short8x w_frag[16];
  #pragma unroll
  for (int s=0;s<16;s++){
    const float* bp = Whh + (size_t)rowA*H_DIM + s*32 + quad*8;
    uint4 u = pack8(bp);
    w_frag[s] = *reinterpret_cast<short8x*>(&u);
  }

  // ---- wave-0 per-gate-value state (tid<64): bias, xg pipeline
  float bias_r = 0.f, xg_cur = 0.f, c_reg = 0.f;
  int row2 = 0, readyBlk = 0;
  if (tid < 64){
    row2 = (tid >> 4)*H_DIM + w*16 + (tid & 15);
    bias_r = dir ? (bih_b[row2] + bhh_b[row2]) : (bih_f[row2] + bhh_f[row2]);
    while (__hip_atomic_load(rdy, __ATOMIC_RELAXED, __HIP_MEMORY_SCOPE_AGENT) != 32u) {}
    (void)__hip_atomic_load(rdy, __ATOMIC_ACQUIRE, __HIP_MEMORY_SCOPE_AGENT);
    readyBlk = 1;
    xg_cur = xg[row2];
  }

  unsigned* hb = hbuf + dir*1024;  // [2][512]

  for (int t = 1; t <= T_LEN; ++t){
    // ---- stage h_{t-1}: poll 2 tagged words/thread, mask bf16 into LDS
    {
      unsigned* s0 = hb + ((t-1)&1)*512 + tid;
      const unsigned want = (unsigned)(t-1);
      unsigned v0 = __hip_atomic_load(s0,     __ATOMIC_RELAXED, __HIP_MEMORY_SCOPE_AGENT);
      unsigned v1 = __hip_atomic_load(s0+256, __ATOMIC_RELAXED, __HIP_MEMORY_SCOPE_AGENT);
      while (((v0 >> 16) != want) || ((v1 >> 16) != want)){
        v0 = __hip_atomic_load(s0,     __ATOMIC_RELAXED, __HIP_MEMORY_SCOPE_AGENT);
        v1 = __hip_atomic_load(s0+256, __ATOMIC_RELAXED, __HIP_MEMORY_SCOPE_AGENT);
      }
      lds_hb[tid]     = (unsigned short)(v0 & 0xffffu);
      lds_hb[tid+256] = (unsigned short)(v1 & 0xffffu);
    }
    __syncthreads();

    // prefetch next step's xg (consumed next iteration), gated on readiness
    float xg_nxt = 0.f;
    if (tid < 64 && t < T_LEN){
      const int nb = t >> 6;
      if (nb >= readyBlk){
        while (__hip_atomic_load(rdy + nb, __ATOMIC_RELAXED, __HIP_MEMORY_SCOPE_AGENT) != 32u) {}
        (void)__hip_atomic_load(rdy + nb, __ATOMIC_ACQUIRE, __HIP_MEMORY_SCOPE_AGENT);
        readyBlk = nb + 1;
      }
      xg_nxt = xg[(size_t)t*G4 + row2];
    }

    // ---- matvec: 16 chained-by-2 MFMAs, B = h broadcast-replicated
    f32x4 a0 = (f32x4){0.f,0.f,0.f,0.f}, a1 = (f32x4){0.f,0.f,0.f,0.f};
    #pragma unroll
    for (int s=0;s<16;s+=2){
      const short8x b0 = *(const short8x*)(lds_hb + s*32     + quad*8);
      const short8x b1 = *(const short8x*)(lds_hb + (s+1)*32 + quad*8);
      a0 = __builtin_amdgcn_mfma_f32_16x16x32_bf16(w_frag[s],   b0, a0, 0, 0, 0);
      a1 = __builtin_amdgcn_mfma_f32_16x16x32_bf16(w_frag[s+1], b1, a1, 0, 0, 0);
    }
    if (col == 0){
      f32x4 asum = a0 + a1;   // D[m] in regs i: m = quad*4+i (same for all cols)
      *reinterpret_cast<f32x4*>(raw + wave*16 + quad*4) = asum;
    }
    __syncthreads();

    // ---- gates + state update, all inside wave 0 (shfl handoff, no barrier)
    if (tid < 64){
      float v = raw[tid] + bias_r + xg_cur;
      const float va = ((tid >> 4) == 2) ? ftanh(v) : sigm(v);
      const int l2 = tid & 15;
      const float iv = __shfl(va, l2);
      const float fv = __shfl(va, l2 + 16);
      const float gg = __shfl(va, l2 + 32);
      const float ov = __shfl(va, l2 + 48);
      if (tid < 16){
        c_reg = fv*c_reg + iv*gg;
        const float hh = ov*ftanh(c_reg);
        const int hj = w*16 + tid;
        const unsigned hv = ((unsigned)t << 16) | (unsigned)f2b(hh);
        __hip_atomic_store(hb + (t&1)*512 + hj, hv,
                           __ATOMIC_RELAXED, __HIP_MEMORY_SCOPE_AGENT);
        const int tt = dir ? (T_LEN - t) : (t - 1);
        enc[(size_t)tt*D_DIM + dir*H_DIM + hj] = hh;
      }
      xg_cur = xg_nxt;
    }
    __syncthreads();  // protect lds_hb / raw reuse next iteration
  }

  // ---- epilogue: block 0 zeroes k_tail grid-barrier counters (hbuf[0..15]).
  // Safe: block 0 reaching here proves every dir-0 block consumed slot-0 tag
  // 1022 (last reader of these words); its own t=1024 publish to the same
  // addresses is ordered before by per-location program order.
  if (blockIdx.x == 0 && tid < 16)
    __hip_atomic_store(hbuf + tid, 0u, __ATOMIC_RELAXED, __HIP_MEMORY_SCOPE_AGENT);
}

// ---------------- k_tail: entire post-lstm pipeline, one launch ---------------
// 256 blocks (1/CU, all co-resident), 8 agent-scope grid barriers between
// phases. Barrier protocol = the xgReady release/acquire pattern (verified).
static __device__ __forceinline__ void gbar(unsigned* c){
  __syncthreads();
  if (threadIdx.x == 0){
    __hip_atomic_fetch_add(c, 1u, __ATOMIC_RELEASE, __HIP_MEMORY_SCOPE_AGENT);
    while (__hip_atomic_load(c, __ATOMIC_RELAXED, __HIP_MEMORY_SCOPE_AGENT) != 256u) {}
    (void)__hip_atomic_load(c, __ATOMIC_ACQUIRE, __HIP_MEMORY_SCOPE_AGENT);
  }
  __syncthreads();
}

static __device__ void gemm_tile(
    const unsigned short* __restrict__ Ah, int lda,
    const unsigned short* __restrict__ Bh, int ldb,
    const float* __restrict__ bias, int act,
    void* __restrict__ Cp, int ldc, int cbf16, int K, int bm, int bn,
    unsigned short* As, unsigned short* Bs)
{
  const int tid = threadIdx.x;
  const int r  = tid >> 2, c8 = (tid & 3) * 8;
  const int wave = tid >> 6, lane = tid & 63;
  const int wm = (wave >> 1) * 32, wn = (wave & 1) * 32;
  const int col = lane & 15, quad = lane >> 4;

  const unsigned short* arow = Ah + (size_t)(bm+r)*lda;
  const unsigned short* brow = Bh + (size_t)(bn+r)*ldb;
  uint4* aw = (uint4*)(As + r*40 + c8);
  uint4* bw = (uint4*)(Bs + r*40 + c8);

  f32x4 acc[2][2];
  #pragma unroll
  for (int i=0;i<2;i++)
    #pragma unroll
    for (int j=0;j<2;j++) acc[i][j] = (f32x4){0.f,0.f,0.f,0.f};

  for (int k0 = 0; k0 < K; k0 += 32){   // K multiple of 32 for all tail GEMMs
    const uint4 avv = *(const uint4*)(arow + k0 + c8);
    const uint4 bvv = *(const uint4*)(brow + k0 + c8);
    __syncthreads();
    *aw = avv; *bw = bvv;
    __syncthreads();
    const short8x a0 = *(const short8x*)(As + (wm+col)*40    + quad*8);
    const short8x a1 = *(const short8x*)(As + (wm+16+col)*40 + quad*8);
    const short8x b0 = *(const short8x*)(Bs + (wn+col)*40    + quad*8);
    const short8x b1 = *(const short8x*)(Bs + (wn+16+col)*40 + quad*8);
    acc[0][0] = __builtin_amdgcn_mfma_f32_16x16x32_bf16(a0, b0, acc[0][0], 0, 0, 0);
    acc[0][1] = __builtin_amdgcn_mfma_f32_16x16x32_bf16(a0, b1, acc[0][1], 0, 0, 0);
    acc[1][0] = __builtin_amdgcn_mfma_f32_16x16x32_bf16(a1, b0, acc[1][0], 0, 0, 0);
    acc[1][1] = __builtin_amdgcn_mfma_f32_16x16x32_bf16(a1, b1, acc[1][1], 0, 0, 0);
  }

  #pragma unroll
  for (int mt=0;mt<2;mt++){
    #pragma unroll
    for (int nt=0;nt<2;nt++){
      const int cc = bn + wn + 16*nt + col;
      const float bs = bias ? bias[cc] : 0.f;
      #pragma unroll
      for (int i=0;i<4;i++){
        const int rr = bm + wm + 16*mt + quad*4 + i;
        float v = acc[mt][nt][i] + bs;
        if (act) v = ftanh(v);
        if (cbf16) ((unsigned short*)Cp)[(size_t)rr*ldc + cc] = f2b(v);
        else       ((float*)Cp)[(size_t)rr*ldc + cc] = v;
      }
    }
  }
}

__global__ __launch_bounds__(256, 1) void k_tail(
    const float* __restrict__ enc,
    unsigned short* __restrict__ cath, unsigned short* __restrict__ encT,
    const float* __restrict__ attn_W, unsigned short* __restrict__ attn_Wh,
    const float* __restrict__ attn_b,
    const float* __restrict__ h2h1_W, unsigned short* __restrict__ h2h1_Wh,
    const float* __restrict__ h2h1_b,
    unsigned short* __restrict__ projh, float* __restrict__ scores,
    unsigned short* __restrict__ scoresh, float* __restrict__ h1,
    const float* __restrict__ tagW, const float* __restrict__ tagb,
    float* __restrict__ feats, const float* __restrict__ trans,
    const int* __restrict__ tags, float* __restrict__ chunkM,
    unsigned* __restrict__ bars, float* __restrict__ out)
{
  __shared__ __align__(16) unsigned short As[64*40];
  __shared__ __align__(16) unsigned short Bs[64*40];
  __shared__ float red[4], red2[4];
  const int tid = threadIdx.x, b = blockIdx.x;
  const int wave = tid >> 6, lane = tid & 63;
  const int bm = (b >> 4) * 64, bn = (b & 15) * 64;

  // ---- phase A: encprep (cath[:, :1024], encT) + attn_W / h2h1_W casts ------
  {
    float (*tile)[33] = (float(*)[33])As;   // 4224 B < 5120 B
    const int tx = tid & 31, ty8 = tid >> 5;
    for (int j = b; j < 1024; j += 256){
      const int bx = (j & 31)*32, by = (j >> 5)*32;
      __syncthreads();
      #pragma unroll
      for (int i=ty8;i<32;i+=8){
        const float v = enc[(size_t)(by+i)*1024 + bx+tx];
        tile[i][tx] = v;
        cath[(size_t)(by+i)*2048 + bx+tx] = f2b(v);
      }
      __syncthreads();
      #pragma unroll
      for (int i=ty8;i<32;i+=8) encT[(size_t)(bx+i)*1024 + by+tx] = f2b(tile[tx][i]);
    }
    const int gid = b*256 + tid;
    for (int c = gid; c < 262144; c += 65536){
      const float4 v = *reinterpret_cast<const float4*>(attn_W + (size_t)c*4);
      ushort2 x, y; x.x=f2b(v.x); x.y=f2b(v.y); y.x=f2b(v.z); y.y=f2b(v.w);
      *reinterpret_cast<ushort2*>(attn_Wh + (size_t)c*4)     = x;
      *reinterpret_cast<ushort2*>(attn_Wh + (size_t)c*4 + 2) = y;
    }
    for (int c = gid; c < 524288; c += 65536){
      const float4 v = *reinterpret_cast<const float4*>(h2h1_W + (size_t)c*4);
      ushort2 x, y; x.x=f2b(v.x); x.y=f2b(v.y); y.x=f2b(v.z); y.y=f2b(v.w);
      *reinterpret_cast<ushort2*>(h2h1_Wh + (size_t)c*4)     = x;
      *reinterpret_cast<ushort2*>(h2h1_Wh + (size_t)c*4 + 2) = y;
    }
  }
  gbar(bars + 0);

  // ---- phase B: projh = bf16(enc * attn_W^T + attn_b) -----------------------
  gemm_tile(cath, 2048, attn_Wh, D_DIM, attn_b, 0, projh, D_DIM, 1, D_DIM, bm, bn, As, Bs);
  gbar(bars + 1);

  // ---- phase C: scores = enc * proj^T (f32) ---------------------------------
  gemm_tile(cath, 2048, projh, D_DIM, nullptr, 0, scores, T_LEN, 0, D_DIM, bm, bn, As, Bs);
  gbar(bars + 2);

  // ---- phase D: row softmax in place + bf16 copy (4 rows/block) -------------
  for (int rr = 0; rr < 4; ++rr){
    float* r = scores + (size_t)(b*4 + rr)*1024;
    unsigned short* rh = scoresh + (size_t)(b*4 + rr)*1024;
    float v[4];
    #pragma unroll
    for (int i=0;i<4;i++) v[i] = r[tid + i*256];
    float m = fmaxf(fmaxf(v[0],v[1]), fmaxf(v[2],v[3]));
    #pragma unroll
    for (int off=32; off>=1; off>>=1) m = fmaxf(m, __shfl_xor(m, off));
    if (lane == 0) red[wave] = m;
    __syncthreads();
    m = fmaxf(fmaxf(red[0],red[1]), fmaxf(red[2],red[3]));
    float s = 0.f;
    #pragma unroll
    for (int i=0;i<4;i++){ v[i] = __expf(v[i]-m); s += v[i]; }
    #pragma unroll
    for (int off=32; off>=1; off>>=1) s += __shfl_xor(s, off);
    if (lane == 0) red2[wave] = s;
    __syncthreads();
    s = red2[0]+red2[1]+red2[2]+red2[3];
    const float inv = frcp(s);
    #pragma unroll
    for (int i=0;i<4;i++){
      const float o = v[i]*inv;
      r[tid + i*256]  = o;
      rh[tid + i*256] = f2b(o);
    }
    __syncthreads();   // red/red2 reuse next row
  }
  gbar(bars + 3);

  // ---- phase E: cath[:, 1024:] = bf16(w * enc) via A=scoresh, B=encT --------
  gemm_tile(scoresh, T_LEN, encT, D_DIM, nullptr, 0, cath + 1024, 2048, 1, T_LEN, bm, bn, As, Bs);
  gbar(bars + 4);

  // ---- phase F: h1 = tanh(cat * h2h1_W^T + h2h1_b), K=2048 (f32) ------------
  gemm_tile(cath, 2048, h2h1_Wh, 2048, h2h1_b, 1, h1, D_DIM, 0, 2048, bm, bn, As, Bs);
  gbar(bars + 5);

  // ---- phase G: feats = h1 * tag_W^T + tag_b (4 timesteps/block) ------------
  for (int j = 0; j < 4; ++j){
    const int t = b*4 + j;
    const float* hr = h1 + (size_t)t*D_DIM;
    float hv[16];
    #pragma unroll
    for (int i=0;i<16;i++) hv[i] = hr[lane + 64*i];
    #pragma unroll
    for (int jj=0;jj<3;jj++){
      const int tag = wave*3 + jj;
      const float* wr = tagW + (size_t)tag*D_DIM;
      float s = 0.f;
      #pragma unroll
      for (int i=0;i<16;i++) s += hv[i]*wr[lane + 64*i];
      #pragma unroll
      for (int off=32; off>=1; off>>=1) s += __shfl_xor(s, off);
      if (lane == 0) feats[(size_t)t*K_TAGS + tag] = s + tagb[tag];
    }
  }
  gbar(bars + 6);

  // ---- phase H: CRF chunk products (blocks 0..63) ---------------------------
  if (b < 64){
    float* sT = (float*)Bs;        // 144 f32
    float* sF = sT + 144;          // 192 f32
    for (int q = tid; q < 144; q += 256) sT[q] = trans[q];
    const int t0 = b*16;
    for (int q = tid; q < 192; q += 256) sF[q] = feats[(size_t)t0*K_TAGS + q];
    __syncthreads();
    if (tid < 12){
      const int r = tid;
      float m[12], nm[12];
      #pragma unroll
      for (int k=0;k<12;k++) m[k] = sT[k*12 + r] + sF[k];
      for (int s=1; s<16; ++s){
        #pragma unroll
        for (int i=0;i<12;i++){
          float v[12]; float mx = -1e30f;
          #pragma unroll
          for (int k=0;k<12;k++){ v[k] = sT[i*12+k] + m[k]; mx = fmaxf(mx, v[k]); }
          float ss = 0.f;
          #pragma unroll
          for (int k=0;k<12;k++) ss += __expf(v[k]-mx);
          nm[i] = sF[s*12+i] + mx + __logf(ss);
        }
        #pragma unroll
        for (int i=0;i<12;i++) m[i] = nm[i];
      }
      #pragma unroll
      for (int k=0;k<12;k++) chunkM[b*144 + k*12 + r] = m[k];
    }
  }
  gbar(bars + 7);

  // ---- phase I: 64-step alpha chain + gold + output (block 0) ---------------
  if (b == 0){
    float alpha = (lane == 10) ? 0.f : -10000.f;
    if (wave == 1){
      float g = 0.f;
      for (int i = lane; i <= T_LEN; i += 64){
        const int to = (i < T_LEN) ? tags[i]   : 11;        // STOP
        const int fr = (i == 0)    ? 10        : tags[i-1]; // START
        g += trans[to*K_TAGS + fr];
        if (i < T_LEN) g += feats[(size_t)i*K_TAGS + tags[i]];
      }
      #pragma unroll
      for (int off=32; off>=1; off>>=1) g += __shfl_xor(g, off);
      if (lane == 0) red[0] = g;
    } else if (wave == 0){
      float pf[12];
      #pragma unroll
      for (int k=0;k<12;k++) pf[k] = (lane < 12) ? chunkM[lane*12 + k] : 0.f;
      for (int c=0; c<64; ++c){
        float av[12];
        #pragma unroll
        for (int j=0;j<12;j++) av[j] = __shfl(alpha, j);
        float cur[12];
        #pragma unroll
        for (int k=0;k<12;k++) cur[k] = pf[k];
        if (c+1 < 64){
          #pragma unroll
          for (int k=0;k<12;k++)
            pf[k] = (lane < 12) ? chunkM[(c+1)*144 + lane*12 + k] : 0.f;
        }
        if (lane < 12){
          float v[12]; float mx = -1e30f;
          #pragma unroll
          for (int k=0;k<12;k++){ v[k] = cur[k] + av[k]; mx = fmaxf(mx, v[k]); }
          float ss = 0.f;
          #pragma unroll
          for (int k=0;k<12;k++) ss += __expf(v[k]-mx);
          alpha = mx + __logf(ss);
        }
      }
    }
    __syncthreads();
    if (wave == 0){
      float v = (lane < K_TAGS) ? (alpha + trans[11*K_TAGS + lane]) : -1e30f;
      float m = v;
      #pragma unroll
      for (int off=32; off>=1; off>>=1) m = fmaxf(m, __shfl_xor(m, off));
      float e = (lane < K_TAGS) ? __expf(v - m) : 0.f;
      #pragma unroll
      for (int off=32; off>=1; off>>=1) e += __shfl_xor(e, off);
      if (lane == 0) out[0] = (m + __logf(e)) - red[0];
    }
  }
}

// ------------------------------------------------------------------------------
extern "C" void kernel_launch(void* const* d_in, const int* in_sizes, int n_in,
                              void* d_out, int out_size, void* d_ws, size_t ws_size,
                              hipStream_t stream)
{
  const int*   sentence = (const int*)d_in[0];
  const int*   tags     = (const int*)d_in[1];
  const float* we       = (const float*)d_in[2];
  const float* Wih_f    = (const float*)d_in[3];
  const float* Whh_f    = (const float*)d_in[4];
  const float* bih_f    = (const float*)d_in[5];
  const float* bhh_f    = (const float*)d_in[6];
  const float* Wih_b    = (const float*)d_in[7];
  const float* Whh_b    = (const float*)d_in[8];
  const float* bih_b    = (const float*)d_in[9];
  const float* bhh_b    = (const float*)d_in[10];
  const float* attn_W   = (const float*)d_in[11];
  const float* attn_b   = (const float*)d_in[12];
  const float* h2h1_W   = (const float*)d_in[13];
  const float* h2h1_b   = (const float*)d_in[14];
  const float* tag_W    = (const float*)d_in[15];
  const float* tag_b    = (const float*)d_in[16];
  const float* trans    = (const float*)d_in[17];
  float* out = (float*)d_out;

  // ---- workspace layout: identical 24 MB footprint, lifetime-aliased --------
  float* ws = (float*)d_ws;
  float* R1 = ws;                    // 2097152 f32 (8 MB)
  float* R2 = ws + 2097152;          // 2097152 f32 (8 MB)
  float* R3 = ws + 4194304;          // 1048576 f32 (4 MB)
  float* R4 = ws + 5242880;          // 1048576 f32 (4 MB)
  float* feats = ws + 6291456;       // 12288 f32
  unsigned* hbuf = (unsigned*)(ws + 6303744);  // 2048 u32 (words 0..15 double as k_tail bars)

  // pre/during-lstm phase
  float* xg_f = R1;                                        // 8 MB f32
  float* xg_b = R2;                                        // 8 MB f32
  float* enc  = R3;                                        // 4 MB f32
  unsigned short* xh      = (unsigned short*)R4;           // 1024*300
  unsigned short* Wih_fh  = (unsigned short*)R4 + 307200;  // 2048*300
  unsigned short* Wih_bh  = (unsigned short*)R4 + 921600;  // 2048*300 (3 MB total)
  unsigned* xgReady = (unsigned*)feats;                    // 32 u32 (feats dead until phase G)
  // post-lstm phase (xg_f/xg_b/xh/Wih_* dead)
  unsigned short* cath    = (unsigned short*)R1;           // [1024][2048] bf16 (4 MB)
  unsigned short* attn_Wh = (unsigned short*)(R1 + 1048576); // 1024*1024 bf16 (2 MB)
  unsigned short* h2h1_Wh = (unsigned short*)R2;           // 1024*2048 bf16 (4 MB)
  float* scores = R2 + 1048576;                            // [1024][1024] f32 (4 MB)
  unsigned short* encT    = (unsigned short*)R4;           // [1024][1024] bf16 (2 MB)
  unsigned short* projh   = (unsigned short*)R4 + 1048576; // [1024][1024] bf16 (2 MB)
  unsigned short* scoresh = (unsigned short*)R3;           // 2 MB (enc dead after phase A)
  float* h1     = R3;                                      // 4 MB f32 (scoresh dead after E)
  float* chunkM = R4;                                      // 36 KB (encT dead after phase E)

  // 1. pre: gather + init + Wih casts
  k_pre<<<dim3(600), dim3(256), 0, stream>>>(sentence, we, xh,
      Wih_f, Wih_fh, Wih_b, Wih_bh, hbuf, xgReady);
  // 2. fused: bidirectional recurrence (blocks 0-63) + xg GEMM producers
  k_lstm_fused<<<dim3(256), dim3(256), 0, stream>>>(Whh_f, Whh_b, bih_f, bhh_f,
      bih_b, bhh_b, xg_f, xg_b, xh, Wih_fh, Wih_bh, hbuf, xgReady, enc);
  // 3. tail: attention + h1 + feats + CRF, single persistent kernel
  k_tail<<<dim3(256), dim3(256), 0, stream>>>(enc, cath, encT,
      attn_W, attn_Wh, attn_b, h2h1_W, h2h1_Wh, h2h1_b,
      projh, scores, scoresh, h1, tag_W, tag_b, feats, trans, tags,
      chunkM, hbuf, out);
}